// Round 5
// baseline (34.615 us; speedup 1.0000x reference)
//
#include <hip/hip_runtime.h>

namespace {

constexpr int OUT_F = 11008;
constexpr int IN_F  = 4096;

typedef int   int4v   __attribute__((ext_vector_type(4)));
typedef float float4v __attribute__((ext_vector_type(4)));

constexpr int ROWS_PER_WAVE   = 2;
constexpr int WAVES_PER_BLOCK = 4;
constexpr int ROWS_PER_BLOCK  = ROWS_PER_WAVE * WAVES_PER_BLOCK;  // 8
constexpr int K_STEPS         = IN_F / (64 * 4);                  // 16 (4 ints/lane/step)
constexpr int CHUNK           = 2;                                // steps per pipeline stage
constexpr int NCHUNK          = K_STEPS / CHUNK;                  // 8
constexpr int DEPTH           = 3;                                // stages in flight

__global__ __launch_bounds__(256, 2) void qlinear_kernel(
    const float* __restrict__ x,       // [4, IN_F]
    const int*   __restrict__ qw,      // [OUT_F, IN_F] int8 values in int32
    const float* __restrict__ scales,  // [OUT_F]
    const float* __restrict__ bias,    // [OUT_F]
    float*       __restrict__ out)     // [4, OUT_F]
{
    // x staged once as fp32 (exact): 64 KB -> 2 blocks/CU (8 waves/CU).
    // Rounds 2 vs 4 showed TLP beyond 8 waves/CU buys nothing; the lever
    // here is per-wave outstanding bytes, not wave count.
    __shared__ float4v xs[4 * (IN_F / 4)];

    const int tid = threadIdx.x;
    const float4v* xg = (const float4v*)x;
#pragma unroll
    for (int j = 0; j < (4 * IN_F / 4) / 256; ++j)
        xs[j * 256 + tid] = xg[j * 256 + tid];
    __syncthreads();

    const int lane = tid & 63;
    const int wid  = tid >> 6;
    const int row0 = blockIdx.x * ROWS_PER_BLOCK + wid * ROWS_PER_WAVE;

    const int4v* wp0 = (const int4v*)(qw + (size_t)row0 * IN_F);
    const int4v* wp1 = (const int4v*)(qw + (size_t)(row0 + 1) * IN_F);

    float acc[ROWS_PER_WAVE][4];
#pragma unroll
    for (int r = 0; r < ROWS_PER_WAVE; ++r)
#pragma unroll
        for (int b = 0; b < 4; ++b)
            acc[r][b] = 0.0f;

    // Depth-3 rolling pipeline, statically indexed (full unroll => every
    // w[][][] access is compile-time; no register copies, no vmcnt(0)
    // drains). While chunk c is consumed, chunks c+1 and c+2 are in flight.
    int4v w[DEPTH][ROWS_PER_WAVE][CHUNK];

#pragma unroll
    for (int p = 0; p < DEPTH - 1; ++p) {
#pragma unroll
        for (int s = 0; s < CHUNK; ++s) {
            w[p][0][s] = wp0[(p * CHUNK + s) * 64 + lane];
            w[p][1][s] = wp1[(p * CHUNK + s) * 64 + lane];
        }
    }

#pragma unroll
    for (int c = 0; c < NCHUNK; ++c) {
        // Issue chunk c+DEPTH-1 into the buffer freed at c-1.
        if (c + DEPTH - 1 < NCHUNK) {
            const int pf = (c + DEPTH - 1) % DEPTH;
#pragma unroll
            for (int s = 0; s < CHUNK; ++s) {
                w[pf][0][s] = wp0[((c + DEPTH - 1) * CHUNK + s) * 64 + lane];
                w[pf][1][s] = wp1[((c + DEPTH - 1) * CHUNK + s) * 64 + lane];
            }
        }

        const int cc = c % DEPTH;
#pragma unroll
        for (int s = 0; s < CHUNK; ++s) {
            const int k = c * CHUNK + s;
            float4v xv[4];
#pragma unroll
            for (int b = 0; b < 4; ++b)
                xv[b] = xs[b * (IN_F / 4) + k * 64 + lane];

#pragma unroll
            for (int r = 0; r < ROWS_PER_WAVE; ++r) {
                float4v wf;
                wf.x = (float)w[cc][r][s].x;
                wf.y = (float)w[cc][r][s].y;
                wf.z = (float)w[cc][r][s].z;
                wf.w = (float)w[cc][r][s].w;
#pragma unroll
                for (int b = 0; b < 4; ++b) {
                    acc[r][b] += wf.x * xv[b].x;
                    acc[r][b] += wf.y * xv[b].y;
                    acc[r][b] += wf.z * xv[b].z;
                    acc[r][b] += wf.w * xv[b].w;
                }
            }
        }
    }

    // Butterfly reduction across the 64 lanes.
#pragma unroll
    for (int r = 0; r < ROWS_PER_WAVE; ++r)
#pragma unroll
        for (int b = 0; b < 4; ++b) {
            float v = acc[r][b];
#pragma unroll
            for (int m = 32; m >= 1; m >>= 1)
                v += __shfl_xor(v, m, 64);
            acc[r][b] = v;
        }

    if (lane == 0) {
#pragma unroll
        for (int r = 0; r < ROWS_PER_WAVE; ++r) {
            const int row = row0 + r;
            const float s  = scales[row];
            const float bz = bias[row];
#pragma unroll
            for (int b = 0; b < 4; ++b)
                out[(size_t)b * OUT_F + row] = acc[r][b] * s + bz;
        }
    }
}

}  // namespace

extern "C" void kernel_launch(void* const* d_in, const int* in_sizes, int n_in,
                              void* d_out, int out_size, void* d_ws, size_t ws_size,
                              hipStream_t stream) {
    const float* x      = (const float*)d_in[0];
    const int*   qw     = (const int*)d_in[1];
    const float* scales = (const float*)d_in[2];
    const float* bias   = (const float*)d_in[3];
    float*       out    = (float*)d_out;

    const int grid = OUT_F / ROWS_PER_BLOCK;  // 1376
    qlinear_kernel<<<grid, 256, 0, stream>>>(x, qw, scales, bias, out);
}